// Round 11
// baseline (238.705 us; speedup 1.0000x reference)
//
#include <hip/hip_runtime.h>
#include <math.h>

static constexpr int kN  = 50000;
static constexpr int kE  = 800000;
static constexpr int kC  = 32;
static constexpr int kH  = 4;
static constexpr int kHC = 128;   // H*C
static constexpr int kB  = 64;
static constexpr int kNB = (kN + 255) / 256;       // 196 scan blocks
static constexpr int kMB = (kN + 127) / 128;       // 391 mfma-proj blocks

typedef __attribute__((ext_vector_type(8))) short bf16x8;
typedef __attribute__((ext_vector_type(4))) float f32x4;

__device__ __forceinline__ unsigned short f2bf(float f) {
    unsigned u = __float_as_uint(f);
    unsigned r = (u + 0x7FFFu + ((u >> 16) & 1u)) >> 16;
    return (unsigned short)r;
}
__device__ __forceinline__ float blo(unsigned u) { return __uint_as_float(u << 16); }
__device__ __forceinline__ float bhi(unsigned u) { return __uint_as_float(u & 0xFFFF0000u); }

// ---------- 1) fused: degree histogram + W^T fragment pack ----------
__global__ __launch_bounds__(256) void hist_packw_kernel(
    const int* __restrict__ ei, int* __restrict__ deg,
    const float* __restrict__ Wq, const float* __restrict__ Wk,
    const float* __restrict__ Wv, const float* __restrict__ Wskip,
    uint4* __restrict__ wtf)
{
    if (blockIdx.x < 16) {
        int tid = blockIdx.x * 256 + threadIdx.x;   // 0..4095
        int f = tid >> 6, l = tid & 63;
        int m = f >> 4, c = (f >> 1) & 7, kk = f & 1;
        int col = c * 16 + (l & 15);
        int k0  = kk * 32 + (l >> 4) * 8;
        const float* Wm = (m == 0) ? Wq : (m == 1) ? Wk : (m == 2) ? Wv : Wskip;
        unsigned p[4];
#pragma unroll
        for (int j = 0; j < 4; ++j) {
            unsigned lo = f2bf(Wm[(k0 + 2 * j) * kHC + col]);
            unsigned hi = f2bf(Wm[(k0 + 2 * j + 1) * kHC + col]);
            p[j] = lo | (hi << 16);
        }
        wtf[f * 64 + l] = make_uint4(p[0], p[1], p[2], p[3]);
        return;
    }
    int i = (blockIdx.x - 16) * 256 + threadIdx.x;
    if (i < kE) atomicAdd(&deg[ei[kE + i]], 1);
}

// ---------- 2) fused: MFMA projections (reg-resident W) + scanA ----------
// Epilogue stages packed rows in LDS, then emits coalesced uint4 stores.
__global__ __launch_bounds__(256) void proj_scanA_kernel(
    const float4* __restrict__ x4,
    const float* __restrict__ bq, const float* __restrict__ bk,
    const float* __restrict__ bv, const float* __restrict__ bskip,
    const uint4* __restrict__ wtf,
    unsigned short* __restrict__ qxb, unsigned short* __restrict__ kvb,
    const int* __restrict__ deg, int* __restrict__ bsum)
{
    __shared__ unsigned stg[2][32 * 128];   // (qx | kv) x 32 nodes x 128 u32 = 32KB
    if (blockIdx.x >= kMB) {   // ---- scanA part ----
        int bid = blockIdx.x - kMB;
        int i = bid * 256 + threadIdx.x;
        int v = (i < kN) ? deg[i] : 0;
#pragma unroll
        for (int s = 1; s < 64; s <<= 1) v += __shfl_xor(v, s);
        if ((threadIdx.x & 63) == 0) stg[0][threadIdx.x >> 6] = (unsigned)v;
        __syncthreads();
        if (threadIdx.x == 0)
            bsum[bid] = (int)(stg[0][0] + stg[0][1] + stg[0][2] + stg[0][3]);
        return;
    }
    const int t = threadIdx.x;
    const int w = t >> 6;          // wave = matrix id
    const int l = t & 63;
    const int l15 = l & 15, l16 = l >> 4;
    const int n0 = blockIdx.x * 128;

    bf16x8 bf[8][2];
#pragma unroll
    for (int c = 0; c < 8; ++c)
#pragma unroll
        for (int kk = 0; kk < 2; ++kk)
            bf[c][kk] = __builtin_bit_cast(bf16x8, wtf[(unsigned)((w * 16 + c * 2 + kk) * 64 + l)]);

    const float* Bm = (w == 0) ? bq : (w == 1) ? bk : (w == 2) ? bv : bskip;
    float bias[8];
#pragma unroll
    for (int c = 0; c < 8; ++c) bias[c] = Bm[c * 16 + l15];

    const int bufid = (w == 0 || w == 3) ? 0 : 1;
    const int add4  = (w >= 2) ? 4 : 0;

    for (int rt = 0; rt < 4; ++rt) {
        const int r0 = n0 + rt * 32 + l15;
        const int r1 = r0 + 16;
        f32x4 acc[2][8];
#pragma unroll
        for (int r = 0; r < 2; ++r)
#pragma unroll
            for (int c = 0; c < 8; ++c)
                acc[r][c] = (f32x4){bias[c], bias[c], bias[c], bias[c]};
#pragma unroll
        for (int kk = 0; kk < 2; ++kk) {
            float4 xa0 = make_float4(0.f,0.f,0.f,0.f), xb0 = xa0, xa1 = xa0, xb1 = xa0;
            if (r0 < kN) {
                xa0 = x4[(size_t)r0 * 16 + kk * 8 + l16 * 2];
                xb0 = x4[(size_t)r0 * 16 + kk * 8 + l16 * 2 + 1];
            }
            if (r1 < kN) {
                xa1 = x4[(size_t)r1 * 16 + kk * 8 + l16 * 2];
                xb1 = x4[(size_t)r1 * 16 + kk * 8 + l16 * 2 + 1];
            }
            uint4 u0 = make_uint4(
                f2bf(xa0.x) | ((unsigned)f2bf(xa0.y) << 16),
                f2bf(xa0.z) | ((unsigned)f2bf(xa0.w) << 16),
                f2bf(xb0.x) | ((unsigned)f2bf(xb0.y) << 16),
                f2bf(xb0.z) | ((unsigned)f2bf(xb0.w) << 16));
            uint4 u1 = make_uint4(
                f2bf(xa1.x) | ((unsigned)f2bf(xa1.y) << 16),
                f2bf(xa1.z) | ((unsigned)f2bf(xa1.w) << 16),
                f2bf(xb1.x) | ((unsigned)f2bf(xb1.y) << 16),
                f2bf(xb1.z) | ((unsigned)f2bf(xb1.w) << 16));
            bf16x8 a0 = __builtin_bit_cast(bf16x8, u0);
            bf16x8 a1 = __builtin_bit_cast(bf16x8, u1);
#pragma unroll
            for (int c = 0; c < 8; ++c) {
                acc[0][c] = __builtin_amdgcn_mfma_f32_16x16x32_bf16(a0, bf[c][kk], acc[0][c], 0, 0, 0);
                acc[1][c] = __builtin_amdgcn_mfma_f32_16x16x32_bf16(a1, bf[c][kk], acc[1][c], 0, 0, 0);
            }
        }
        // stage packed u32 in final row layout (even lanes only)
#pragma unroll
        for (int r = 0; r < 2; ++r) {
#pragma unroll
            for (int j = 0; j < 4; ++j) {
                int nn = r * 16 + l16 * 4 + j;     // local node 0..31
#pragma unroll
                for (int c = 0; c < 8; ++c) {
                    float v0 = acc[r][c][j];
                    float v1 = __shfl_xor(v0, 1);
                    if ((l & 1) == 0) {
                        int jcol = c * 16 + l15;    // even
                        int gpos = ((jcol >> 2) << 3) | (jcol & 3);
                        stg[bufid][nn * 128 + ((gpos + add4) >> 1)] =
                            f2bf(v0) | ((unsigned)f2bf(v1) << 16);
                    }
                }
            }
        }
        __syncthreads();
        // coalesced flush: 2048 uint4 by 256 threads
#pragma unroll
        for (int i = 0; i < 8; ++i) {
            int idx = i * 256 + t;
            int buf = idx >> 10;
            int rem = idx & 1023;
            int nn  = rem >> 5;
            int q4  = rem & 31;
            int node = n0 + rt * 32 + nn;
            if (node < kN)
                ((uint4*)(buf ? kvb : qxb))[(size_t)node * 32 + q4] =
                    *(const uint4*)&stg[buf][nn * 128 + q4 * 4];
        }
        __syncthreads();
    }
}

// ---------- 3) CSR: per-block scan with folded global scan of block sums ----------
__global__ __launch_bounds__(256) void scanC2_kernel(
    const int* __restrict__ deg, const int* __restrict__ bsum,
    int* __restrict__ rowptr, int* __restrict__ cursor)
{
    __shared__ int bsh[256];
    __shared__ int sh[256];
    const int t = threadIdx.x, i = blockIdx.x * 256 + t;
    int bv = (t < kNB) ? bsum[t] : 0;
    bsh[t] = bv; __syncthreads();
    for (int off = 1; off < 256; off <<= 1) {
        int u = (t >= off) ? bsh[t - off] : 0;
        __syncthreads();
        bsh[t] += u;
        __syncthreads();
    }
    const int bofs = (blockIdx.x == 0) ? 0 : bsh[blockIdx.x - 1];
    if (blockIdx.x == 0 && t == 0) rowptr[kN] = bsh[kNB - 1];
    int v = (i < kN) ? deg[i] : 0;
    sh[t] = v; __syncthreads();
    for (int off = 1; off < 256; off <<= 1) {
        int u = (t >= off) ? sh[t - off] : 0;
        __syncthreads();
        sh[t] += u;
        __syncthreads();
    }
    if (i < kN) {
        int ex = sh[t] - v + bofs;
        rowptr[i] = ex;
        cursor[i] = ex;
    }
}

// ---------- 4) CSR: scatter packed 4B (src:u16 | ea:bf16) ----------
__global__ __launch_bounds__(256) void scatter_kernel(
    const int* __restrict__ ei, const float* __restrict__ ea,
    int* __restrict__ cursor, unsigned* __restrict__ csr)
{
    int i = blockIdx.x * 256 + threadIdx.x;
    if (i >= kE) return;
    int dst = ei[kE + i];
    int slot = atomicAdd(&cursor[dst], 1);
    csr[slot] = (unsigned)ei[i] | ((unsigned)f2bf(ea[i]) << 16);
}

// ---------- 5) per-node softmax attention (no-max-sub exp2 form) + epilogue ----------
// 512 threads = 8 waves = 8 nodes per block; half = lane>>5 picks one of 2
// concurrent edges; sl = lane&31 owns channels [4sl..4sl+3]; head = sl>>3.
__global__ __launch_bounds__(512) void node_attn_kernel(
    const int* __restrict__ rowptr, const unsigned* __restrict__ csr,
    const unsigned short* __restrict__ qxb, const unsigned short* __restrict__ kvb,
    const float* __restrict__ We, const float* __restrict__ be,
    const float* __restrict__ Wbeta, const float* __restrict__ Wlin,
    const float* __restrict__ blin, float* __restrict__ hbuf)
{
    __shared__ float wlS[kHC * kC];   // 16 KB
    __shared__ float wbS[3 * kHC];
    __shared__ float oshS[8][kHC];
    const int t = threadIdx.x, wv = t >> 6, lane = t & 63;
    for (int i = t; i < kHC * kC; i += 512) wlS[i] = Wlin[i];
    for (int i = t; i < 3 * kHC; i += 512) wbS[i] = Wbeta[i];
    __syncthreads();

    const int node = blockIdx.x * 8 + wv;    // grid covers exactly kN
    const int half = lane >> 5;
    const int sl   = lane & 31;
    const int ch   = sl * 4;
    const float4 we4 = *(const float4*)&We[ch];
    const float4 be4 = *(const float4*)&be[ch];
    const float4 wbA = *(const float4*)&wbS[ch];
    const float4 wbB = *(const float4*)&wbS[kHC + ch];
    const float4 wbC = *(const float4*)&wbS[2 * kHC + ch];
    const float blc = blin[sl];
    // 1/sqrt(32) * log2(e): logits pre-scaled for direct v_exp_f32 (2^x)
    const float A2 = 0.17677669529663687f * 1.44269504088896341f;

    const uint4 qx = *((const uint4*)(qxb + (size_t)node * 256) + sl);
    const float q0 = blo(qx.x), q1 = bhi(qx.x), q2v = blo(qx.y), q3 = bhi(qx.y);
    const float xr0 = blo(qx.z), xr1 = bhi(qx.z), xr2 = blo(qx.w), xr3 = bhi(qx.w);
    float qw = q0 * we4.x + q1 * we4.y + q2v * we4.z + q3 * we4.w;
    float qe = q0 * be4.x + q1 * be4.y + q2v * be4.z + q3 * be4.w;
    qw += __shfl_xor(qw, 1); qe += __shfl_xor(qe, 1);
    qw += __shfl_xor(qw, 2); qe += __shfl_xor(qe, 2);
    qw += __shfl_xor(qw, 4); qe += __shfl_xor(qe, 4);
    const float qwA = qw * A2, qbA = qe * A2;

    float ss = 0.f, swa = 0.f;
    float ax0 = 0.f, ax1 = 0.f, ax2 = 0.f, ax3 = 0.f;
    const int beg = rowptr[node], end = rowptr[node + 1];
    int e = beg;
    for (; e + 3 < end; e += 4) {
        unsigned cA = csr[e + half];
        unsigned cB = csr[e + 2 + half];
        float aA = bhi(cA), aB = bhi(cB);
        const uint4 uA = *((const uint4*)(kvb + (size_t)(cA & 0xFFFFu) * 256) + sl);
        const uint4 uB = *((const uint4*)(kvb + (size_t)(cB & 0xFFFFu) * 256) + sl);
        float pA = fmaf(q3, bhi(uA.y), fmaf(q2v, blo(uA.y), fmaf(q1, bhi(uA.x), q0 * blo(uA.x))));
        float pB = fmaf(q3, bhi(uB.y), fmaf(q2v, blo(uB.y), fmaf(q1, bhi(uB.x), q0 * blo(uB.x))));
        pA += __shfl_xor(pA, 1); pB += __shfl_xor(pB, 1);
        pA += __shfl_xor(pA, 2); pB += __shfl_xor(pB, 2);
        pA += __shfl_xor(pA, 4); pB += __shfl_xor(pB, 4);
        float eA = __builtin_amdgcn_exp2f(fmaf(pA, A2, fmaf(aA, qwA, qbA)));
        float eB = __builtin_amdgcn_exp2f(fmaf(pB, A2, fmaf(aB, qwA, qbA)));
        ss  += eA + eB;
        swa = fmaf(eA, aA, fmaf(eB, aB, swa));
        ax0 = fmaf(eA, blo(uA.z), fmaf(eB, blo(uB.z), ax0));
        ax1 = fmaf(eA, bhi(uA.z), fmaf(eB, bhi(uB.z), ax1));
        ax2 = fmaf(eA, blo(uA.w), fmaf(eB, blo(uB.w), ax2));
        ax3 = fmaf(eA, bhi(uA.w), fmaf(eB, bhi(uB.w), ax3));
    }
    for (; e < end; e += 2) {
        int idx = e + half;
        bool valid = idx < end;
        unsigned cA = csr[valid ? idx : end - 1];
        float aA = bhi(cA);
        const uint4 uA = *((const uint4*)(kvb + (size_t)(cA & 0xFFFFu) * 256) + sl);
        float pA = fmaf(q3, bhi(uA.y), fmaf(q2v, blo(uA.y), fmaf(q1, bhi(uA.x), q0 * blo(uA.x))));
        pA += __shfl_xor(pA, 1);
        pA += __shfl_xor(pA, 2);
        pA += __shfl_xor(pA, 4);
        float eA = valid ? __builtin_amdgcn_exp2f(fmaf(pA, A2, fmaf(aA, qwA, qbA))) : 0.f;
        ss  += eA;
        swa = fmaf(eA, aA, swa);
        ax0 = fmaf(eA, blo(uA.z), ax0);
        ax1 = fmaf(eA, bhi(uA.z), ax1);
        ax2 = fmaf(eA, blo(uA.w), ax2);
        ax3 = fmaf(eA, bhi(uA.w), ax3);
    }
    // merge the two half-wave streams (pure adds — no max state)
    ss  += __shfl_xor(ss , 32);
    swa += __shfl_xor(swa, 32);
    ax0 += __shfl_xor(ax0, 32);
    ax1 += __shfl_xor(ax1, 32);
    ax2 += __shfl_xor(ax2, 32);
    ax3 += __shfl_xor(ax3, 32);

    // val = (ax + swa*We + ss*be) / ss   (0 for isolated nodes)
    float rcp = 1.f / fmaxf(ss, 1e-16f);
    float v0 = fmaf(swa, we4.x, fmaf(ss, be4.x, ax0)) * rcp;
    float v1 = fmaf(swa, we4.y, fmaf(ss, be4.y, ax1)) * rcp;
    float v2 = fmaf(swa, we4.z, fmaf(ss, be4.z, ax2)) * rcp;
    float v3 = fmaf(swa, we4.w, fmaf(ss, be4.w, ax3)) * rcp;
    float part = wbA.x * v0 + wbA.y * v1 + wbA.z * v2 + wbA.w * v3
               + wbB.x * xr0 + wbB.y * xr1 + wbB.z * xr2 + wbB.w * xr3
               + wbC.x * (v0 - xr0) + wbC.y * (v1 - xr1)
               + wbC.z * (v2 - xr2) + wbC.w * (v3 - xr3);
    part += __shfl_xor(part, 1);
    part += __shfl_xor(part, 2);
    part += __shfl_xor(part, 4);
    part += __shfl_xor(part, 8);
    part += __shfl_xor(part, 16);
    float beta = 1.f / (1.f + __expf(-part));
    float o0 = beta * xr0 + (1.f - beta) * v0;
    float o1 = beta * xr1 + (1.f - beta) * v1;
    float o2 = beta * xr2 + (1.f - beta) * v2;
    float o3 = beta * xr3 + (1.f - beta) * v3;
    if (half == 0) *(float4*)&oshS[wv][ch] = make_float4(o0, o1, o2, o3);
    __builtin_amdgcn_wave_barrier();
    float hp = 0.f;
#pragma unroll
    for (int jj = 0; jj < 64; ++jj) {
        int j = half * 64 + jj;
        hp = fmaf(oshS[wv][j], wlS[j * kC + sl], hp);
    }
    hp += __shfl_xor(hp, 32);
    if (lane < 32) hbuf[(size_t)node * kC + sl] = fmaxf(hp + blc, 0.f);
}

// ---------- 6a) GraphNorm stats ----------
__global__ __launch_bounds__(256) void gn_reduce_kernel(
    const float* __restrict__ hbuf, const int* __restrict__ batch,
    const float* __restrict__ gms, float* __restrict__ stats)
{
    const int g = blockIdx.x;
    const int t = threadIdx.x;
    __shared__ int se[2];
    __shared__ float s1[8][kC], s2[8][kC];
    if (t < 2) {
        int target = g + t;
        int lo = 0, hi = kN;
        while (lo < hi) { int mid = (lo + hi) >> 1; if (batch[mid] < target) lo = mid + 1; else hi = mid; }
        se[t] = lo;
    }
    __syncthreads();
    int start = se[0], end = se[1];
    float cnt = fmaxf((float)(end - start), 1.f);
    int c = t & 31, r = t >> 5;
    float a = 0.f, b = 0.f;
    for (int n = start + r; n < end; n += 8) {
        float v = hbuf[(size_t)n * kC + c];
        a += v; b = fmaf(v, v, b);
    }
    s1[r][c] = a; s2[r][c] = b;
    __syncthreads();
    if (t < kC) {
        float sa = 0.f, sb = 0.f;
#pragma unroll
        for (int i = 0; i < 8; ++i) { sa += s1[i][t]; sb += s2[i][t]; }
        float mean = sa / cnt;
        float ms   = mean * gms[t];
        float var  = sb / cnt - 2.f * ms * mean + ms * ms;
        stats[g * 64 + t]      = ms;
        stats[g * 64 + 32 + t] = rsqrtf(var + 1e-5f);
    }
}

// ---------- 6b) GraphNorm apply ----------
__global__ __launch_bounds__(256) void gn_apply_kernel(
    const float* __restrict__ hbuf, const int* __restrict__ batch,
    const float* __restrict__ stats,
    const float* __restrict__ gw, const float* __restrict__ gb,
    float* __restrict__ out)
{
    int idx = blockIdx.x * 256 + threadIdx.x;
    if (idx >= kN * kC) return;
    int n = idx >> 5, c = idx & 31;
    int g = batch[n];
    float ms   = stats[g * 64 + c];
    float rstd = stats[g * 64 + 32 + c];
    float v = hbuf[idx];
    out[idx] = fmaf(gw[c] * (v - ms), rstd, gb[c]);
}

extern "C" void kernel_launch(void* const* d_in, const int* in_sizes, int n_in,
                              void* d_out, int out_size, void* d_ws, size_t ws_size,
                              hipStream_t stream) {
    (void)in_sizes; (void)n_in; (void)out_size; (void)ws_size;
    const float* x     = (const float*)d_in[0];
    const int*   ei    = (const int*)d_in[1];
    const float* ea    = (const float*)d_in[2];
    const int*   batch = (const int*)d_in[3];
    const float* Wq    = (const float*)d_in[4];
    const float* bq    = (const float*)d_in[5];
    const float* Wk    = (const float*)d_in[6];
    const float* bk    = (const float*)d_in[7];
    const float* Wv    = (const float*)d_in[8];
    const float* bv    = (const float*)d_in[9];
    const float* We    = (const float*)d_in[10];
    const float* be    = (const float*)d_in[11];
    const float* Wskip = (const float*)d_in[12];
    const float* bskip = (const float*)d_in[13];
    const float* Wbeta = (const float*)d_in[14];
    const float* Wlin  = (const float*)d_in[15];
    const float* blin  = (const float*)d_in[16];
    const float* gw    = (const float*)d_in[17];
    const float* gb    = (const float*)d_in[18];
    const float* gms   = (const float*)d_in[19];
    float* out = (float*)d_out;

    char* ws = (char*)d_ws;
    unsigned* csr = (unsigned*)ws;        ws += (size_t)kE * 4;
    unsigned short* qxb = (unsigned short*)ws; ws += (size_t)kN * 256 * 2;
    unsigned short* kvb = (unsigned short*)ws; ws += (size_t)kN * 256 * 2;
    float* hbuf   = (float*)ws;           ws += (size_t)kN * kC * 4;
    int*   deg    = (int*)ws;             ws += (size_t)kN * 4;
    int*   cursor = (int*)ws;             ws += (size_t)kN * 4;
    int*   rowptr = (int*)ws;             ws += (size_t)(kN + 1) * 4;
    int*   bsum   = (int*)ws;             ws += (size_t)kNB * 4;
    float* stats  = (float*)ws;           ws += (size_t)kB * 64 * 4;
    uint4* wtf    = (uint4*)ws;           ws += (size_t)64 * 64 * 16;

    hipMemsetAsync(deg, 0, (size_t)kN * 4, stream);

    hist_packw_kernel<<<16 + (kE + 255) / 256, 256, 0, stream>>>(
        ei, deg, Wq, Wk, Wv, Wskip, wtf);
    proj_scanA_kernel<<<kMB + kNB, 256, 0, stream>>>(
        (const float4*)x, bq, bk, bv, bskip, wtf, qxb, kvb, deg, bsum);
    scanC2_kernel<<<kNB, 256, 0, stream>>>(deg, bsum, rowptr, cursor);
    scatter_kernel<<<(kE + 255) / 256, 256, 0, stream>>>(ei, ea, cursor, csr);
    node_attn_kernel<<<kN / 8, 512, 0, stream>>>(
        rowptr, csr, qxb, kvb, We, be, Wbeta, Wlin, blin, hbuf);
    gn_reduce_kernel<<<kB, 256, 0, stream>>>(hbuf, batch, gms, stats);
    gn_apply_kernel<<<(kN * kC + 255) / 256, 256, 0, stream>>>(
        hbuf, batch, stats, gw, gb, out);
}

// Round 12
// 219.766 us; speedup vs baseline: 1.0862x; 1.0862x over previous
//
#include <hip/hip_runtime.h>
#include <math.h>

static constexpr int kN  = 50000;
static constexpr int kE  = 800000;
static constexpr int kC  = 32;
static constexpr int kH  = 4;
static constexpr int kHC = 128;   // H*C
static constexpr int kB  = 64;
static constexpr int kNB = (kN + 255) / 256;       // 196 scan blocks
static constexpr int kMB = (kN + 127) / 128;       // 391 mfma-proj blocks

typedef __attribute__((ext_vector_type(8))) short bf16x8;
typedef __attribute__((ext_vector_type(4))) float f32x4;

__device__ __forceinline__ unsigned short f2bf(float f) {
    unsigned u = __float_as_uint(f);
    unsigned r = (u + 0x7FFFu + ((u >> 16) & 1u)) >> 16;
    return (unsigned short)r;
}
__device__ __forceinline__ float blo(unsigned u) { return __uint_as_float(u << 16); }
__device__ __forceinline__ float bhi(unsigned u) { return __uint_as_float(u & 0xFFFF0000u); }

// ---------- 1) fused: degree histogram + W^T fragment pack ----------
__global__ __launch_bounds__(256) void hist_packw_kernel(
    const int* __restrict__ ei, int* __restrict__ deg,
    const float* __restrict__ Wq, const float* __restrict__ Wk,
    const float* __restrict__ Wv, const float* __restrict__ Wskip,
    uint4* __restrict__ wtf)
{
    if (blockIdx.x < 16) {
        int tid = blockIdx.x * 256 + threadIdx.x;   // 0..4095
        int f = tid >> 6, l = tid & 63;
        int m = f >> 4, c = (f >> 1) & 7, kk = f & 1;
        int col = c * 16 + (l & 15);
        int k0  = kk * 32 + (l >> 4) * 8;
        const float* Wm = (m == 0) ? Wq : (m == 1) ? Wk : (m == 2) ? Wv : Wskip;
        unsigned p[4];
#pragma unroll
        for (int j = 0; j < 4; ++j) {
            unsigned lo = f2bf(Wm[(k0 + 2 * j) * kHC + col]);
            unsigned hi = f2bf(Wm[(k0 + 2 * j + 1) * kHC + col]);
            p[j] = lo | (hi << 16);
        }
        wtf[f * 64 + l] = make_uint4(p[0], p[1], p[2], p[3]);
        return;
    }
    int i = (blockIdx.x - 16) * 256 + threadIdx.x;
    if (i < kE) atomicAdd(&deg[ei[kE + i]], 1);
}

// ---------- 2) fused: MFMA projections (reg-resident W, direct stores) + scanA ----------
__global__ __launch_bounds__(256) void proj_scanA_kernel(
    const float4* __restrict__ x4,
    const float* __restrict__ bq, const float* __restrict__ bk,
    const float* __restrict__ bv, const float* __restrict__ bskip,
    const uint4* __restrict__ wtf,
    unsigned short* __restrict__ qxb, unsigned short* __restrict__ kvb,
    const int* __restrict__ deg, int* __restrict__ bsum)
{
    __shared__ int sh4[4];
    if (blockIdx.x >= kMB) {   // ---- scanA part ----
        int bid = blockIdx.x - kMB;
        int i = bid * 256 + threadIdx.x;
        int v = (i < kN) ? deg[i] : 0;
#pragma unroll
        for (int s = 1; s < 64; s <<= 1) v += __shfl_xor(v, s);
        if ((threadIdx.x & 63) == 0) sh4[threadIdx.x >> 6] = v;
        __syncthreads();
        if (threadIdx.x == 0) bsum[bid] = sh4[0] + sh4[1] + sh4[2] + sh4[3];
        return;
    }
    const int t = threadIdx.x;
    const int w = t >> 6;          // wave = matrix id
    const int l = t & 63;
    const int l15 = l & 15, l16 = l >> 4;
    const int n0 = blockIdx.x * 128;

    bf16x8 bf[8][2];
#pragma unroll
    for (int c = 0; c < 8; ++c)
#pragma unroll
        for (int kk = 0; kk < 2; ++kk)
            bf[c][kk] = __builtin_bit_cast(bf16x8, wtf[(unsigned)((w * 16 + c * 2 + kk) * 64 + l)]);

    const float* Bm = (w == 0) ? bq : (w == 1) ? bk : (w == 2) ? bv : bskip;
    float bias[8];
#pragma unroll
    for (int c = 0; c < 8; ++c) bias[c] = Bm[c * 16 + l15];

    unsigned short* dst = (w == 0 || w == 3) ? qxb : kvb;
    const int add4 = (w >= 2) ? 4 : 0;

    for (int rt = 0; rt < 4; ++rt) {
        const int r0 = n0 + rt * 32 + l15;
        const int r1 = r0 + 16;
        f32x4 acc[2][8];
#pragma unroll
        for (int r = 0; r < 2; ++r)
#pragma unroll
            for (int c = 0; c < 8; ++c)
                acc[r][c] = (f32x4){bias[c], bias[c], bias[c], bias[c]};
#pragma unroll
        for (int kk = 0; kk < 2; ++kk) {
            float4 xa0 = make_float4(0.f,0.f,0.f,0.f), xb0 = xa0, xa1 = xa0, xb1 = xa0;
            if (r0 < kN) {
                xa0 = x4[(size_t)r0 * 16 + kk * 8 + l16 * 2];
                xb0 = x4[(size_t)r0 * 16 + kk * 8 + l16 * 2 + 1];
            }
            if (r1 < kN) {
                xa1 = x4[(size_t)r1 * 16 + kk * 8 + l16 * 2];
                xb1 = x4[(size_t)r1 * 16 + kk * 8 + l16 * 2 + 1];
            }
            uint4 u0 = make_uint4(
                f2bf(xa0.x) | ((unsigned)f2bf(xa0.y) << 16),
                f2bf(xa0.z) | ((unsigned)f2bf(xa0.w) << 16),
                f2bf(xb0.x) | ((unsigned)f2bf(xb0.y) << 16),
                f2bf(xb0.z) | ((unsigned)f2bf(xb0.w) << 16));
            uint4 u1 = make_uint4(
                f2bf(xa1.x) | ((unsigned)f2bf(xa1.y) << 16),
                f2bf(xa1.z) | ((unsigned)f2bf(xa1.w) << 16),
                f2bf(xb1.x) | ((unsigned)f2bf(xb1.y) << 16),
                f2bf(xb1.z) | ((unsigned)f2bf(xb1.w) << 16));
            bf16x8 a0 = __builtin_bit_cast(bf16x8, u0);
            bf16x8 a1 = __builtin_bit_cast(bf16x8, u1);
#pragma unroll
            for (int c = 0; c < 8; ++c) {
                acc[0][c] = __builtin_amdgcn_mfma_f32_16x16x32_bf16(a0, bf[c][kk], acc[0][c], 0, 0, 0);
                acc[1][c] = __builtin_amdgcn_mfma_f32_16x16x32_bf16(a1, bf[c][kk], acc[1][c], 0, 0, 0);
            }
        }
#pragma unroll
        for (int r = 0; r < 2; ++r) {
#pragma unroll
            for (int j = 0; j < 4; ++j) {
                int node = n0 + rt * 32 + r * 16 + l16 * 4 + j;
                bool valid = (node < kN) && ((l & 1) == 0);
                size_t base = (size_t)node * 128;   // uint offset of row
#pragma unroll
                for (int c = 0; c < 8; ++c) {
                    float v0 = acc[r][c][j];
                    float v1 = __shfl_xor(v0, 1);
                    if (valid) {
                        int jcol = c * 16 + l15;    // even
                        int gpos = ((jcol >> 2) << 3) | (jcol & 3);
                        unsigned pk = f2bf(v0) | ((unsigned)f2bf(v1) << 16);
                        ((unsigned*)dst)[base + ((gpos + add4) >> 1)] = pk;
                    }
                }
            }
        }
    }
}

// ---------- 3) CSR: per-block scan with folded global scan of block sums ----------
__global__ __launch_bounds__(256) void scanC2_kernel(
    const int* __restrict__ deg, const int* __restrict__ bsum,
    int* __restrict__ rowptr, int* __restrict__ cursor)
{
    __shared__ int bsh[256];
    __shared__ int sh[256];
    const int t = threadIdx.x, i = blockIdx.x * 256 + t;
    int bv = (t < kNB) ? bsum[t] : 0;
    bsh[t] = bv; __syncthreads();
    for (int off = 1; off < 256; off <<= 1) {
        int u = (t >= off) ? bsh[t - off] : 0;
        __syncthreads();
        bsh[t] += u;
        __syncthreads();
    }
    const int bofs = (blockIdx.x == 0) ? 0 : bsh[blockIdx.x - 1];
    if (blockIdx.x == 0 && t == 0) rowptr[kN] = bsh[kNB - 1];
    int v = (i < kN) ? deg[i] : 0;
    sh[t] = v; __syncthreads();
    for (int off = 1; off < 256; off <<= 1) {
        int u = (t >= off) ? sh[t - off] : 0;
        __syncthreads();
        sh[t] += u;
        __syncthreads();
    }
    if (i < kN) {
        int ex = sh[t] - v + bofs;
        rowptr[i] = ex;
        cursor[i] = ex;
    }
}

// ---------- 4) CSR: scatter packed 4B (src:u16 | ea:bf16) ----------
__global__ __launch_bounds__(256) void scatter_kernel(
    const int* __restrict__ ei, const float* __restrict__ ea,
    int* __restrict__ cursor, unsigned* __restrict__ csr)
{
    int i = blockIdx.x * 256 + threadIdx.x;
    if (i >= kE) return;
    int dst = ei[kE + i];
    int slot = atomicAdd(&cursor[dst], 1);
    csr[slot] = (unsigned)ei[i] | ((unsigned)f2bf(ea[i]) << 16);
}

// ---------- 5) per-node softmax attention (no-max-sub exp2 form) + epilogue ----------
// 512 threads = 8 waves = 8 nodes per block; half = lane>>5 picks one of 2
// concurrent edges; sl = lane&31 owns channels [4sl..4sl+3]; head = sl>>3.
__global__ __launch_bounds__(512) void node_attn_kernel(
    const int* __restrict__ rowptr, const unsigned* __restrict__ csr,
    const unsigned short* __restrict__ qxb, const unsigned short* __restrict__ kvb,
    const float* __restrict__ We, const float* __restrict__ be,
    const float* __restrict__ Wbeta, const float* __restrict__ Wlin,
    const float* __restrict__ blin, float* __restrict__ hbuf)
{
    __shared__ float wlS[kHC * kC];   // 16 KB
    __shared__ float wbS[3 * kHC];
    __shared__ float oshS[8][kHC];
    const int t = threadIdx.x, wv = t >> 6, lane = t & 63;
    for (int i = t; i < kHC * kC; i += 512) wlS[i] = Wlin[i];
    for (int i = t; i < 3 * kHC; i += 512) wbS[i] = Wbeta[i];
    __syncthreads();

    const int node = blockIdx.x * 8 + wv;    // grid covers exactly kN
    const int half = lane >> 5;
    const int sl   = lane & 31;
    const int ch   = sl * 4;
    const float4 we4 = *(const float4*)&We[ch];
    const float4 be4 = *(const float4*)&be[ch];
    const float4 wbA = *(const float4*)&wbS[ch];
    const float4 wbB = *(const float4*)&wbS[kHC + ch];
    const float4 wbC = *(const float4*)&wbS[2 * kHC + ch];
    const float blc = blin[sl];
    // 1/sqrt(32) * log2(e): logits pre-scaled for direct v_exp_f32 (2^x)
    const float A2 = 0.17677669529663687f * 1.44269504088896341f;

    const uint4 qx = *((const uint4*)(qxb + (size_t)node * 256) + sl);
    const float q0 = blo(qx.x), q1 = bhi(qx.x), q2v = blo(qx.y), q3 = bhi(qx.y);
    const float xr0 = blo(qx.z), xr1 = bhi(qx.z), xr2 = blo(qx.w), xr3 = bhi(qx.w);
    float qw = q0 * we4.x + q1 * we4.y + q2v * we4.z + q3 * we4.w;
    float qe = q0 * be4.x + q1 * be4.y + q2v * be4.z + q3 * be4.w;
    qw += __shfl_xor(qw, 1); qe += __shfl_xor(qe, 1);
    qw += __shfl_xor(qw, 2); qe += __shfl_xor(qe, 2);
    qw += __shfl_xor(qw, 4); qe += __shfl_xor(qe, 4);
    const float qwA = qw * A2, qbA = qe * A2;

    float ss = 0.f, swa = 0.f;
    float ax0 = 0.f, ax1 = 0.f, ax2 = 0.f, ax3 = 0.f;
    const int beg = rowptr[node], end = rowptr[node + 1];
    int e = beg;
    for (; e + 3 < end; e += 4) {
        unsigned cA = csr[e + half];
        unsigned cB = csr[e + 2 + half];
        float aA = bhi(cA), aB = bhi(cB);
        const uint4 uA = *((const uint4*)(kvb + (size_t)(cA & 0xFFFFu) * 256) + sl);
        const uint4 uB = *((const uint4*)(kvb + (size_t)(cB & 0xFFFFu) * 256) + sl);
        float pA = fmaf(q3, bhi(uA.y), fmaf(q2v, blo(uA.y), fmaf(q1, bhi(uA.x), q0 * blo(uA.x))));
        float pB = fmaf(q3, bhi(uB.y), fmaf(q2v, blo(uB.y), fmaf(q1, bhi(uB.x), q0 * blo(uB.x))));
        pA += __shfl_xor(pA, 1); pB += __shfl_xor(pB, 1);
        pA += __shfl_xor(pA, 2); pB += __shfl_xor(pB, 2);
        pA += __shfl_xor(pA, 4); pB += __shfl_xor(pB, 4);
        float eA = __builtin_amdgcn_exp2f(fmaf(pA, A2, fmaf(aA, qwA, qbA)));
        float eB = __builtin_amdgcn_exp2f(fmaf(pB, A2, fmaf(aB, qwA, qbA)));
        ss  += eA + eB;
        swa = fmaf(eA, aA, fmaf(eB, aB, swa));
        ax0 = fmaf(eA, blo(uA.z), fmaf(eB, blo(uB.z), ax0));
        ax1 = fmaf(eA, bhi(uA.z), fmaf(eB, bhi(uB.z), ax1));
        ax2 = fmaf(eA, blo(uA.w), fmaf(eB, blo(uB.w), ax2));
        ax3 = fmaf(eA, bhi(uA.w), fmaf(eB, bhi(uB.w), ax3));
    }
    for (; e < end; e += 2) {
        int idx = e + half;
        bool valid = idx < end;
        unsigned cA = csr[valid ? idx : end - 1];
        float aA = bhi(cA);
        const uint4 uA = *((const uint4*)(kvb + (size_t)(cA & 0xFFFFu) * 256) + sl);
        float pA = fmaf(q3, bhi(uA.y), fmaf(q2v, blo(uA.y), fmaf(q1, bhi(uA.x), q0 * blo(uA.x))));
        pA += __shfl_xor(pA, 1);
        pA += __shfl_xor(pA, 2);
        pA += __shfl_xor(pA, 4);
        float eA = valid ? __builtin_amdgcn_exp2f(fmaf(pA, A2, fmaf(aA, qwA, qbA))) : 0.f;
        ss  += eA;
        swa = fmaf(eA, aA, swa);
        ax0 = fmaf(eA, blo(uA.z), ax0);
        ax1 = fmaf(eA, bhi(uA.z), ax1);
        ax2 = fmaf(eA, blo(uA.w), ax2);
        ax3 = fmaf(eA, bhi(uA.w), ax3);
    }
    // merge the two half-wave streams (pure adds — no max state)
    ss  += __shfl_xor(ss , 32);
    swa += __shfl_xor(swa, 32);
    ax0 += __shfl_xor(ax0, 32);
    ax1 += __shfl_xor(ax1, 32);
    ax2 += __shfl_xor(ax2, 32);
    ax3 += __shfl_xor(ax3, 32);

    // val = (ax + swa*We + ss*be) / ss   (0 for isolated nodes)
    float rcp = 1.f / fmaxf(ss, 1e-16f);
    float v0 = fmaf(swa, we4.x, fmaf(ss, be4.x, ax0)) * rcp;
    float v1 = fmaf(swa, we4.y, fmaf(ss, be4.y, ax1)) * rcp;
    float v2 = fmaf(swa, we4.z, fmaf(ss, be4.z, ax2)) * rcp;
    float v3 = fmaf(swa, we4.w, fmaf(ss, be4.w, ax3)) * rcp;
    float part = wbA.x * v0 + wbA.y * v1 + wbA.z * v2 + wbA.w * v3
               + wbB.x * xr0 + wbB.y * xr1 + wbB.z * xr2 + wbB.w * xr3
               + wbC.x * (v0 - xr0) + wbC.y * (v1 - xr1)
               + wbC.z * (v2 - xr2) + wbC.w * (v3 - xr3);
    part += __shfl_xor(part, 1);
    part += __shfl_xor(part, 2);
    part += __shfl_xor(part, 4);
    part += __shfl_xor(part, 8);
    part += __shfl_xor(part, 16);
    float beta = 1.f / (1.f + __expf(-part));
    float o0 = beta * xr0 + (1.f - beta) * v0;
    float o1 = beta * xr1 + (1.f - beta) * v1;
    float o2 = beta * xr2 + (1.f - beta) * v2;
    float o3 = beta * xr3 + (1.f - beta) * v3;
    if (half == 0) *(float4*)&oshS[wv][ch] = make_float4(o0, o1, o2, o3);
    __builtin_amdgcn_wave_barrier();
    float hp = 0.f;
#pragma unroll
    for (int jj = 0; jj < 64; ++jj) {
        int j = half * 64 + jj;
        hp = fmaf(oshS[wv][j], wlS[j * kC + sl], hp);
    }
    hp += __shfl_xor(hp, 32);
    if (lane < 32) hbuf[(size_t)node * kC + sl] = fmaxf(hp + blc, 0.f);
}

// ---------- 6) GraphNorm fused: one block per graph, reduce + apply ----------
__global__ __launch_bounds__(512) void gn_kernel(
    const float* __restrict__ hbuf, const int* __restrict__ batch,
    const float* __restrict__ gms,
    const float* __restrict__ gw, const float* __restrict__ gb,
    float* __restrict__ out)
{
    const int g = blockIdx.x;
    const int t = threadIdx.x;
    __shared__ int se[2];
    __shared__ float s1[16][kC], s2[16][kC];
    __shared__ float msS[kC], rsS[kC];
    if (t < 2) {
        int target = g + t;
        int lo = 0, hi = kN;
        while (lo < hi) { int mid = (lo + hi) >> 1; if (batch[mid] < target) lo = mid + 1; else hi = mid; }
        se[t] = lo;
    }
    __syncthreads();
    int start = se[0], end = se[1];
    float cnt = fmaxf((float)(end - start), 1.f);
    int c = t & 31, r = t >> 5;    // r in 0..15
    float a = 0.f, b = 0.f;
    for (int n = start + r; n < end; n += 16) {
        float v = hbuf[(size_t)n * kC + c];
        a += v; b = fmaf(v, v, b);
    }
    s1[r][c] = a; s2[r][c] = b;
    __syncthreads();
    if (t < kC) {
        float sa = 0.f, sb = 0.f;
#pragma unroll
        for (int i = 0; i < 16; ++i) { sa += s1[i][t]; sb += s2[i][t]; }
        float mean = sa / cnt;
        float ms   = mean * gms[t];
        float var  = sb / cnt - 2.f * ms * mean + ms * ms;
        msS[t] = ms;
        rsS[t] = rsqrtf(var + 1e-5f);
    }
    __syncthreads();
    float ms = msS[c], rs = rsS[c], w = gw[c], bb = gb[c];
    for (int n = start + r; n < end; n += 16) {
        float v = hbuf[(size_t)n * kC + c];
        out[(size_t)n * kC + c] = fmaf(w * (v - ms), rs, bb);
    }
}

extern "C" void kernel_launch(void* const* d_in, const int* in_sizes, int n_in,
                              void* d_out, int out_size, void* d_ws, size_t ws_size,
                              hipStream_t stream) {
    (void)in_sizes; (void)n_in; (void)out_size; (void)ws_size;
    const float* x     = (const float*)d_in[0];
    const int*   ei    = (const int*)d_in[1];
    const float* ea    = (const float*)d_in[2];
    const int*   batch = (const int*)d_in[3];
    const float* Wq    = (const float*)d_in[4];
    const float* bq    = (const float*)d_in[5];
    const float* Wk    = (const float*)d_in[6];
    const float* bk    = (const float*)d_in[7];
    const float* Wv    = (const float*)d_in[8];
    const float* bv    = (const float*)d_in[9];
    const float* We    = (const float*)d_in[10];
    const float* be    = (const float*)d_in[11];
    const float* Wskip = (const float*)d_in[12];
    const float* bskip = (const float*)d_in[13];
    const float* Wbeta = (const float*)d_in[14];
    const float* Wlin  = (const float*)d_in[15];
    const float* blin  = (const float*)d_in[16];
    const float* gw    = (const float*)d_in[17];
    const float* gb    = (const float*)d_in[18];
    const float* gms   = (const float*)d_in[19];
    float* out = (float*)d_out;

    char* ws = (char*)d_ws;
    unsigned* csr = (unsigned*)ws;        ws += (size_t)kE * 4;
    unsigned short* qxb = (unsigned short*)ws; ws += (size_t)kN * 256 * 2;
    unsigned short* kvb = (unsigned short*)ws; ws += (size_t)kN * 256 * 2;
    float* hbuf   = (float*)ws;           ws += (size_t)kN * kC * 4;
    int*   deg    = (int*)ws;             ws += (size_t)kN * 4;
    int*   cursor = (int*)ws;             ws += (size_t)kN * 4;
    int*   rowptr = (int*)ws;             ws += (size_t)(kN + 1) * 4;
    int*   bsum   = (int*)ws;             ws += (size_t)kNB * 4;
    uint4* wtf    = (uint4*)ws;           ws += (size_t)64 * 64 * 16;

    hipMemsetAsync(deg, 0, (size_t)kN * 4, stream);

    hist_packw_kernel<<<16 + (kE + 255) / 256, 256, 0, stream>>>(
        ei, deg, Wq, Wk, Wv, Wskip, wtf);
    proj_scanA_kernel<<<kMB + kNB, 256, 0, stream>>>(
        (const float4*)x, bq, bk, bv, bskip, wtf, qxb, kvb, deg, bsum);
    scanC2_kernel<<<kNB, 256, 0, stream>>>(deg, bsum, rowptr, cursor);
    scatter_kernel<<<(kE + 255) / 256, 256, 0, stream>>>(ei, ea, cursor, csr);
    node_attn_kernel<<<kN / 8, 512, 0, stream>>>(
        rowptr, csr, qxb, kvb, We, be, Wbeta, Wlin, blin, hbuf);
    gn_kernel<<<kB, 512, 0, stream>>>(hbuf, batch, gms, gw, gb, out);
}